// Round 2
// 175.854 us; speedup vs baseline: 1.0239x; 1.0239x over previous
//
#include <hip/hip_runtime.h>
#include <math.h>

// Problem constants (reference: B=4, N=8192, points are [B,N,3] fp32)
#define BATCH 4
#define NPTS 8192
#define BN (BATCH * NPTS)
#define NZB 16                 // 4 searches x 4 batches
#define QK 8                   // queries per lane in the scan
#define QBLK (256 * QK)        // 2048 queries per scan block
#define SUBT 64                // provenance subtile (rescan covers this many)
#define SPL 32                 // candidate slices per search

// Workspace layout:
//   [0]        double acc
//   [8]        uint   ticket
//   [64]       int    idx_all[NZB*NPTS]                (512 KB)
//   [64+512K]  u64    packed[NZB*NPTS]                 (1 MB, init 0xFF..)
// packed[q] = (monotonic_key(dmin) << 32) | global_subtile_id
// u64 atomicMin == lexmin(d, g): exact replacement for the old merge pass.

__device__ __forceinline__ void pick_ab(int z, const float* pw, const float* pp,
                                        const float* tw, const float* tp,
                                        const float** qa, const float** cb) {
  if (z == 0)      { *qa = pw; *cb = pp; }
  else if (z == 1) { *qa = pp; *cb = pw; }
  else if (z == 2) { *qa = tw; *cb = tp; }
  else             { *qa = tp; *cb = tw; }
}

// ---------------------------------------------------------------------------
// Pass 0: init packed[] to "no candidate" (key=0xFFFFFFFF > any real key),
// and zero the loss accumulator + ticket. Replaces hipMemsetAsync (which is
// a graph-capture risk in this harness).
// ---------------------------------------------------------------------------
__global__ __launch_bounds__(256) void init_kernel(
    unsigned long long* __restrict__ packed, double* __restrict__ acc,
    unsigned int* __restrict__ ticket) {
  const int gid = blockIdx.x * 256 + threadIdx.x;
  packed[gid] = 0xFFFFFFFFFFFFFFFFULL;
  if (gid == 0) { *acc = 0.0; *ticket = 0u; }
}

// ---------------------------------------------------------------------------
// Pass 1: min-distance scan + subtile provenance (hot loop UNCHANGED from the
// proven ~84us version). Tail folds the cross-slice merge into a single
// device-scope u64 atomicMin per (query, slice) instead of 21 MB of partials.
// Monotonic float->uint key: pos -> bits^0x80000000, neg -> ~bits. Equal keys
// resolve to the smaller subtile id (low word), matching the old strict-<
// first-min semantics across subtiles.
// ---------------------------------------------------------------------------
__global__ __launch_bounds__(256, 4) void nn_partial_kernel(
    const float* __restrict__ pw, const float* __restrict__ pp,
    const float* __restrict__ tw, const float* __restrict__ tp,
    unsigned long long* __restrict__ packed) {
  constexpr int SLICE = NPTS / SPL;   // 256
  constexpr int NSUB = SLICE / SUBT;  // 4
  __shared__ float4 sh[SLICE];

  const int zb = blockIdx.z;
  const int z = zb >> 2;
  const int b = zb & 3;
  const float* qa;
  const float* cb;
  pick_ab(z, pw, pp, tw, tp, &qa, &cb);

  const int tid = threadIdx.x;
  const int cslice = blockIdx.y * SLICE;
  const float* cbb = cb + (size_t)b * NPTS * 3;

  // Stage slice as (x,y,z,||b||^2); formulas must match rescan exactly.
  for (int m = tid; m < SLICE; m += 256) {
    const float* c = cbb + (size_t)(cslice + m) * 3;
    const float bx = c[0], by = c[1], bz = c[2];
    sh[m] = make_float4(bx, by, bz, fmaf(bx, bx, fmaf(by, by, bz * bz)));
  }
  __syncthreads();

  const int qbase = blockIdx.x * QBLK;
  float qx[QK], qy[QK], qz[QK], dmin[QK];
  int tile[QK];
  #pragma unroll
  for (int k = 0; k < QK; ++k) {
    const int n = qbase + tid + k * 256;
    const float* q = qa + ((size_t)b * NPTS + n) * 3;
    qx[k] = -2.0f * q[0];
    qy[k] = -2.0f * q[1];
    qz[k] = -2.0f * q[2];
    dmin[k] = INFINITY;
    tile[k] = 0;
  }

  for (int sub = 0; sub < NSUB; ++sub) {
    float pre[QK];
    #pragma unroll
    for (int k = 0; k < QK; ++k) pre[k] = dmin[k];

    const int cb0 = sub * SUBT;
    #pragma unroll 2
    for (int p = 0; p < SUBT / 2; ++p) {
      const float4 c0 = sh[cb0 + 2 * p];
      const float4 c1 = sh[cb0 + 2 * p + 1];
      float t0[QK], t1[QK];
      #pragma unroll
      for (int k = 0; k < QK; ++k)
        t0[k] = fmaf(qx[k], c0.x, fmaf(qy[k], c0.y, fmaf(qz[k], c0.z, c0.w)));
      #pragma unroll
      for (int k = 0; k < QK; ++k)
        t1[k] = fmaf(qx[k], c1.x, fmaf(qy[k], c1.y, fmaf(qz[k], c1.z, c1.w)));
      #pragma unroll
      for (int k = 0; k < QK; ++k)
        dmin[k] = fminf(fminf(t0[k], t1[k]), dmin[k]);   // v_min3_f32
    }
    const int g = blockIdx.y * NSUB + sub;   // global subtile id, [0,128)
    #pragma unroll
    for (int k = 0; k < QK; ++k)
      tile[k] = (dmin[k] < pre[k]) ? g : tile[k];  // strict <: first-min kept
  }

  #pragma unroll
  for (int k = 0; k < QK; ++k) {
    const int n = qbase + tid + k * 256;
    const unsigned int fb = __float_as_uint(dmin[k]);
    const unsigned int key =
        fb ^ ((fb & 0x80000000u) ? 0xFFFFFFFFu : 0x80000000u);
    const unsigned long long pk =
        ((unsigned long long)key << 32) | (unsigned int)tile[k];
    atomicMin(&packed[(size_t)zb * NPTS + n], pk);  // fire-and-forget, L2-hot
  }
}

// ---------------------------------------------------------------------------
// Pass 2 (tiny): rescan only. The merge already happened via atomicMin.
// One wave resolves 8 queries: unpack (best_d, g), re-evaluate the 64
// candidates of subtile g with the EXACT pass-1 formula, ballot the first
// bitwise match (= first-index tie-break within the subtile, as before).
// ---------------------------------------------------------------------------
__global__ __launch_bounds__(256) void nn_rescan_kernel(
    const float* __restrict__ pw, const float* __restrict__ pp,
    const float* __restrict__ tw, const float* __restrict__ tp,
    const unsigned long long* __restrict__ packed,
    int* __restrict__ idx_all) {
  const int tid = threadIdx.x;
  const int wv = tid >> 6;          // wave id, 0..3
  const int lane = tid & 63;
  const int qid0 = blockIdx.x * 32; // 32 queries/block (8192 % 32 == 0 -> one zb)

  const int zb = qid0 >> 13;        // uniform per block
  const int z = zb >> 2;
  const int b = zb & 3;
  const float* qa;
  const float* cbp;
  pick_ab(z, pw, pp, tw, tp, &qa, &cbp);
  const float* qb0 = qa + (size_t)b * NPTS * 3;
  const float* cbb = cbp + (size_t)b * NPTS * 3;
  const int n0 = qid0 & (NPTS - 1);

  #pragma unroll
  for (int j = 0; j < 8; ++j) {
    const int lq = wv * 8 + j;
    const unsigned long long pk = packed[qid0 + lq];
    const int best_g = (int)(pk & 0xFFFFFFFFULL);
    const unsigned int key = (unsigned int)(pk >> 32);
    const unsigned int fb =
        (key & 0x80000000u) ? (key ^ 0x80000000u) : ~key;
    const float best_d = __uint_as_float(fb);

    const float* q = qb0 + (size_t)(n0 + lq) * 3;   // wave-uniform 12B
    const float qx = -2.0f * q[0];
    const float qy = -2.0f * q[1];
    const float qz = -2.0f * q[2];
    const int m = best_g * SUBT + lane;             // contiguous across wave
    const float* c = cbb + (size_t)m * 3;
    const float bx = c[0], by = c[1], bz = c[2];
    const float b2 = fmaf(bx, bx, fmaf(by, by, bz * bz));
    const float dd = fmaf(qx, bx, fmaf(qy, by, fmaf(qz, bz, b2)));
    const unsigned long long hit = __ballot(dd == best_d);
    if (lane == 0)
      idx_all[qid0 + lq] = best_g * SUBT + (__ffsll((long long)hit) - 1);
  }
}

// ---------------------------------------------------------------------------
// Pass 3: loss (4 MSN terms split across blockIdx.y) + fused finalize.
// One acc-atomic per block; ordering via the atomic's RETURN VALUE (forces
// completion at the device coherence point) before the ticket bump — no
// __threadfence needed. Last of the 512 blocks reads acc and writes out.
// loss = 0.25 * (sum of 4 squared-norm sums) / (B*N)
// ---------------------------------------------------------------------------
__device__ __forceinline__ float3 ld3(const float* __restrict__ p, int i) {
  const float* q = p + (size_t)i * 3;
  return make_float3(q[0], q[1], q[2]);
}

__device__ __forceinline__ float diff_nrm2(float3 a1, float3 a2, float3 b1, float3 b2) {
  const float x = (a1.x - a2.x) - (b1.x - b2.x);
  const float y = (a1.y - a2.y) - (b1.y - b2.y);
  const float z = (a1.z - a2.z) - (b1.z - b2.z);
  return fmaf(x, x, fmaf(y, y, z * z));
}

__global__ __launch_bounds__(256) void loss_final_kernel(
    const float* __restrict__ pw, const float* __restrict__ pp,
    const float* __restrict__ tw, const float* __restrict__ tp,
    const int* __restrict__ ipw, const int* __restrict__ itw,
    const int* __restrict__ ipp, const int* __restrict__ itp,
    const int* __restrict__ idx_all, double* __restrict__ acc,
    unsigned int* __restrict__ ticket, float* __restrict__ out) {
  __shared__ double sd[4];

  const int gid = blockIdx.x * 256 + threadIdx.x;  // [0, B*N)
  const int term = blockIdx.y;
  const int b = gid >> 13;
  const int n = gid & (NPTS - 1);
  const int base = b * NPTS;

  const float* PW = pw + (size_t)base * 3;
  const float* PP = pp + (size_t)base * 3;
  const float* TW = tw + (size_t)base * 3;
  const float* TP = tp + (size_t)base * 3;
  const int* I1P = idx_all + (0 * BATCH + b) * NPTS;  // NN pial for white (pred)
  const int* I2P = idx_all + (1 * BATCH + b) * NPTS;  // NN white for pial (pred)
  const int* I1T = idx_all + (2 * BATCH + b) * NPTS;  // NN pial for white (true)
  const int* I2T = idx_all + (3 * BATCH + b) * NPTS;  // NN white for pial (true)

  float sv;
  if (term == 0) {        // msn(yp_inner, yt_inner[i_pred_white])
    const int j = ipw[base + n];
    sv = diff_nrm2(ld3(PP, I1P[n]), ld3(PW, n), ld3(TP, I1T[j]), ld3(TW, j));
  } else if (term == 1) { // msn(yp_inner[i_true_white], yt_inner)
    const int k = itw[base + n];
    sv = diff_nrm2(ld3(PP, I1P[k]), ld3(PW, k), ld3(TP, I1T[n]), ld3(TW, n));
  } else if (term == 2) { // msn(yp_outer, yt_outer[i_pred_pial])
    const int j = ipp[base + n];
    sv = diff_nrm2(ld3(PP, n), ld3(PW, I2P[n]), ld3(TP, j), ld3(TW, I2T[j]));
  } else {                // msn(yp_outer[i_true_pial], yt_outer)
    const int k = itp[base + n];
    sv = diff_nrm2(ld3(PP, k), ld3(PW, I2P[k]), ld3(TP, n), ld3(TW, I2T[n]));
  }

  // Wave shuffle-reduce -> LDS -> single block sum.
  double ds = (double)sv;
  #pragma unroll
  for (int o = 32; o > 0; o >>= 1) ds += __shfl_down(ds, o, 64);
  if ((threadIdx.x & 63) == 0) sd[threadIdx.x >> 6] = ds;
  __syncthreads();

  if (threadIdx.x == 0) {
    const double bsum = sd[0] + sd[1] + sd[2] + sd[3];
    const double old = atomicAdd(acc, bsum);   // return forces completion
    // Data-dependency on 'old' orders the ticket bump after the acc add.
    const unsigned int inc = 1u + (unsigned int)(((unsigned long long)
                             __double_as_longlong(old)) & 0ull);
    const unsigned int total = gridDim.x * gridDim.y;   // 512
    const unsigned int t = atomicAdd(ticket, inc);
    if (t == total - 1u) {
      const double fin = atomicAdd(acc, 0.0);  // atomic read of the full sum
      out[0] = (float)(0.25 * fin / (double)BN);
    }
  }
}

// ---------------------------------------------------------------------------
extern "C" void kernel_launch(void* const* d_in, const int* in_sizes, int n_in,
                              void* d_out, int out_size, void* d_ws, size_t ws_size,
                              hipStream_t stream) {
  const float* pw = (const float*)d_in[0];
  const float* pp = (const float*)d_in[1];
  const float* tw = (const float*)d_in[2];
  const float* tp = (const float*)d_in[3];
  const int* ipw = (const int*)d_in[4];
  const int* itw = (const int*)d_in[5];
  const int* ipp = (const int*)d_in[6];
  const int* itp = (const int*)d_in[7];
  char* ws = (char*)d_ws;
  float* out = (float*)d_out;

  double* acc = (double*)ws;
  unsigned int* ticket = (unsigned int*)(ws + 8);
  int* idx_all = (int*)(ws + 64);
  unsigned long long* packed =
      (unsigned long long*)(ws + 64 + (size_t)NZB * NPTS * 4);

  init_kernel<<<(NZB * NPTS) / 256, 256, 0, stream>>>(packed, acc, ticket);

  dim3 grid_nn(NPTS / QBLK, SPL, NZB);
  nn_partial_kernel<<<grid_nn, 256, 0, stream>>>(pw, pp, tw, tp, packed);

  nn_rescan_kernel<<<(NZB * NPTS) / 32, 256, 0, stream>>>(
      pw, pp, tw, tp, packed, idx_all);

  dim3 grid_loss(BN / 256, 4);
  loss_final_kernel<<<grid_loss, 256, 0, stream>>>(
      pw, pp, tw, tp, ipw, itw, ipp, itp, idx_all, acc, ticket, out);
}

// Round 3
// 173.969 us; speedup vs baseline: 1.0350x; 1.0108x over previous
//
#include <hip/hip_runtime.h>
#include <math.h>

// Problem constants (reference: B=4, N=8192, points are [B,N,3] fp32)
#define BATCH 4
#define NPTS 8192
#define BN (BATCH * NPTS)
#define NZB 16                 // 4 searches x 4 batches
#define QK 8                   // queries per lane in the scan
#define QBLK (256 * QK)        // 2048 queries per scan block
#define SUBT 64                // provenance subtile (rescan covers this many)
#define SPL 32                 // candidate slices per search

// Packed-fp32 pair (VOP3P v_pk_fma_f32 on gfx90a+/gfx950): one instruction =
// two IEEE fmas per lane. Per-half rounding identical to scalar fmaf, so the
// rescan formula still matches pass-1 bitwise.
typedef float f32x2 __attribute__((ext_vector_type(2)));

__device__ __forceinline__ f32x2 pk_fma(f32x2 a, float b, f32x2 c) {
#if __has_builtin(__builtin_elementwise_fma)
  return __builtin_elementwise_fma(a, (f32x2){b, b}, c);
#else
  return (f32x2){fmaf(a.x, b, c.x), fmaf(a.y, b, c.y)};
#endif
}
__device__ __forceinline__ f32x2 pk_min(f32x2 a, f32x2 b) {
#if __has_builtin(__builtin_elementwise_min)
  return __builtin_elementwise_min(a, b);
#else
  return (f32x2){fminf(a.x, b.x), fminf(a.y, b.y)};
#endif
}

// Workspace layout:
//   [0]        double acc
//   [8]        uint   ticket
//   [64]       int    idx_all[NZB*NPTS]                (512 KB)
//   [64+512K]  u64    packed[NZB*NPTS]                 (1 MB, init 0xFF..)
// packed[q] = (monotonic_key(dmin) << 32) | global_subtile_id
// u64 atomicMin == lexmin(d, g): exact replacement for the old merge pass.

__device__ __forceinline__ void pick_ab(int z, const float* pw, const float* pp,
                                        const float* tw, const float* tp,
                                        const float** qa, const float** cb) {
  if (z == 0)      { *qa = pw; *cb = pp; }
  else if (z == 1) { *qa = pp; *cb = pw; }
  else if (z == 2) { *qa = tw; *cb = tp; }
  else             { *qa = tp; *cb = tw; }
}

// ---------------------------------------------------------------------------
// Pass 0: init packed[] to "no candidate" (key=0xFFFFFFFF > any real key),
// and zero the loss accumulator + ticket.
// ---------------------------------------------------------------------------
__global__ __launch_bounds__(256) void init_kernel(
    unsigned long long* __restrict__ packed, double* __restrict__ acc,
    unsigned int* __restrict__ ticket) {
  const int gid = blockIdx.x * 256 + threadIdx.x;
  packed[gid] = 0xFFFFFFFFFFFFFFFFULL;
  if (gid == 0) { *acc = 0.0; *ticket = 0u; }
}

// ---------------------------------------------------------------------------
// Pass 1: min-distance scan + subtile provenance. Hot loop now uses packed
// fp32 (v_pk_fma_f32): 4 query-pairs instead of 8 scalar queries -> 24 pk_fma
// + 8 v_min3 per 2 candidates (was 48 fma + 8 min3). Issue-bound kernel, so
// fewer instructions = proportional speedup. Numerics bit-identical.
// Tail: cross-slice merge via one device-scope u64 atomicMin per query/slice.
// Monotonic float->uint key: pos -> bits^0x80000000, neg -> ~bits. Equal keys
// resolve to the smaller subtile id (low word) = old strict-< semantics.
// ---------------------------------------------------------------------------
__global__ __launch_bounds__(256, 4) void nn_partial_kernel(
    const float* __restrict__ pw, const float* __restrict__ pp,
    const float* __restrict__ tw, const float* __restrict__ tp,
    unsigned long long* __restrict__ packed) {
  constexpr int SLICE = NPTS / SPL;   // 256
  constexpr int NSUB = SLICE / SUBT;  // 4
  constexpr int QP = QK / 2;          // query pairs per lane
  __shared__ float4 sh[SLICE];

  const int zb = blockIdx.z;
  const int z = zb >> 2;
  const int b = zb & 3;
  const float* qa;
  const float* cb;
  pick_ab(z, pw, pp, tw, tp, &qa, &cb);

  const int tid = threadIdx.x;
  const int cslice = blockIdx.y * SLICE;
  const float* cbb = cb + (size_t)b * NPTS * 3;

  // Stage slice as (x,y,z,||b||^2); formulas must match rescan exactly.
  for (int m = tid; m < SLICE; m += 256) {
    const float* c = cbb + (size_t)(cslice + m) * 3;
    const float bx = c[0], by = c[1], bz = c[2];
    sh[m] = make_float4(bx, by, bz, fmaf(bx, bx, fmaf(by, by, bz * bz)));
  }
  __syncthreads();

  const int qbase = blockIdx.x * QBLK;
  f32x2 qx2[QP], qy2[QP], qz2[QP], dmin2[QP];
  int tile[QK];
  #pragma unroll
  for (int i = 0; i < QP; ++i) {
    const int n0 = qbase + tid + (2 * i) * 256;
    const int n1 = qbase + tid + (2 * i + 1) * 256;
    const float* q0 = qa + ((size_t)b * NPTS + n0) * 3;
    const float* q1 = qa + ((size_t)b * NPTS + n1) * 3;
    qx2[i] = (f32x2){-2.0f * q0[0], -2.0f * q1[0]};
    qy2[i] = (f32x2){-2.0f * q0[1], -2.0f * q1[1]};
    qz2[i] = (f32x2){-2.0f * q0[2], -2.0f * q1[2]};
    dmin2[i] = (f32x2){INFINITY, INFINITY};
    tile[2 * i] = 0;
    tile[2 * i + 1] = 0;
  }

  for (int sub = 0; sub < NSUB; ++sub) {
    f32x2 pre[QP];
    #pragma unroll
    for (int i = 0; i < QP; ++i) pre[i] = dmin2[i];

    const int cb0 = sub * SUBT;
    #pragma unroll 2
    for (int p = 0; p < SUBT / 2; ++p) {
      const float4 c0 = sh[cb0 + 2 * p];
      const float4 c1 = sh[cb0 + 2 * p + 1];
      f32x2 t0[QP], t1[QP];
      #pragma unroll
      for (int i = 0; i < QP; ++i)
        t0[i] = pk_fma(qx2[i], c0.x,
                 pk_fma(qy2[i], c0.y,
                  pk_fma(qz2[i], c0.z, (f32x2){c0.w, c0.w})));
      #pragma unroll
      for (int i = 0; i < QP; ++i)
        t1[i] = pk_fma(qx2[i], c1.x,
                 pk_fma(qy2[i], c1.y,
                  pk_fma(qz2[i], c1.z, (f32x2){c1.w, c1.w})));
      #pragma unroll
      for (int i = 0; i < QP; ++i)
        dmin2[i] = pk_min(pk_min(t0[i], t1[i]), dmin2[i]);  // 2x v_min3_f32
    }
    const int g = blockIdx.y * NSUB + sub;   // global subtile id, [0,128)
    #pragma unroll
    for (int i = 0; i < QP; ++i) {           // strict <: first-min kept
      tile[2 * i]     = (dmin2[i].x < pre[i].x) ? g : tile[2 * i];
      tile[2 * i + 1] = (dmin2[i].y < pre[i].y) ? g : tile[2 * i + 1];
    }
  }

  #pragma unroll
  for (int k = 0; k < QK; ++k) {
    const int n = qbase + tid + k * 256;
    const float dk = (k & 1) ? dmin2[k >> 1].y : dmin2[k >> 1].x;
    const unsigned int fb = __float_as_uint(dk);
    const unsigned int key =
        fb ^ ((fb & 0x80000000u) ? 0xFFFFFFFFu : 0x80000000u);
    const unsigned long long pk =
        ((unsigned long long)key << 32) | (unsigned int)tile[k];
    atomicMin(&packed[(size_t)zb * NPTS + n], pk);  // fire-and-forget, L2-hot
  }
}

// ---------------------------------------------------------------------------
// Pass 2 (tiny): rescan only. The merge already happened via atomicMin.
// One wave resolves 8 queries: unpack (best_d, g), re-evaluate the 64
// candidates of subtile g with the EXACT pass-1 formula, ballot the first
// bitwise match (= first-index tie-break within the subtile, as before).
// ---------------------------------------------------------------------------
__global__ __launch_bounds__(256) void nn_rescan_kernel(
    const float* __restrict__ pw, const float* __restrict__ pp,
    const float* __restrict__ tw, const float* __restrict__ tp,
    const unsigned long long* __restrict__ packed,
    int* __restrict__ idx_all) {
  const int tid = threadIdx.x;
  const int wv = tid >> 6;          // wave id, 0..3
  const int lane = tid & 63;
  const int qid0 = blockIdx.x * 32; // 32 queries/block (one zb per block)

  const int zb = qid0 >> 13;        // uniform per block
  const int z = zb >> 2;
  const int b = zb & 3;
  const float* qa;
  const float* cbp;
  pick_ab(z, pw, pp, tw, tp, &qa, &cbp);
  const float* qb0 = qa + (size_t)b * NPTS * 3;
  const float* cbb = cbp + (size_t)b * NPTS * 3;
  const int n0 = qid0 & (NPTS - 1);

  #pragma unroll
  for (int j = 0; j < 8; ++j) {
    const int lq = wv * 8 + j;
    const unsigned long long pk = packed[qid0 + lq];
    const int best_g = (int)(pk & 0xFFFFFFFFULL);
    const unsigned int key = (unsigned int)(pk >> 32);
    const unsigned int fb =
        (key & 0x80000000u) ? (key ^ 0x80000000u) : ~key;
    const float best_d = __uint_as_float(fb);

    const float* q = qb0 + (size_t)(n0 + lq) * 3;   // wave-uniform 12B
    const float qx = -2.0f * q[0];
    const float qy = -2.0f * q[1];
    const float qz = -2.0f * q[2];
    const int m = best_g * SUBT + lane;             // contiguous across wave
    const float* c = cbb + (size_t)m * 3;
    const float bx = c[0], by = c[1], bz = c[2];
    const float b2 = fmaf(bx, bx, fmaf(by, by, bz * bz));
    const float dd = fmaf(qx, bx, fmaf(qy, by, fmaf(qz, bz, b2)));
    const unsigned long long hit = __ballot(dd == best_d);
    if (lane == 0)
      idx_all[qid0 + lq] = best_g * SUBT + (__ffsll((long long)hit) - 1);
  }
}

// ---------------------------------------------------------------------------
// Pass 3: loss (4 MSN terms split across blockIdx.y) + fused finalize.
// One acc-atomic per block; ordering via the atomic's RETURN VALUE (forces
// completion at the device coherence point) before the ticket bump — no
// __threadfence needed. Last of the 512 blocks reads acc and writes out.
// loss = 0.25 * (sum of 4 squared-norm sums) / (B*N)
// ---------------------------------------------------------------------------
__device__ __forceinline__ float3 ld3(const float* __restrict__ p, int i) {
  const float* q = p + (size_t)i * 3;
  return make_float3(q[0], q[1], q[2]);
}

__device__ __forceinline__ float diff_nrm2(float3 a1, float3 a2, float3 b1, float3 b2) {
  const float x = (a1.x - a2.x) - (b1.x - b2.x);
  const float y = (a1.y - a2.y) - (b1.y - b2.y);
  const float z = (a1.z - a2.z) - (b1.z - b2.z);
  return fmaf(x, x, fmaf(y, y, z * z));
}

__global__ __launch_bounds__(256) void loss_final_kernel(
    const float* __restrict__ pw, const float* __restrict__ pp,
    const float* __restrict__ tw, const float* __restrict__ tp,
    const int* __restrict__ ipw, const int* __restrict__ itw,
    const int* __restrict__ ipp, const int* __restrict__ itp,
    const int* __restrict__ idx_all, double* __restrict__ acc,
    unsigned int* __restrict__ ticket, float* __restrict__ out) {
  __shared__ double sd[4];

  const int gid = blockIdx.x * 256 + threadIdx.x;  // [0, B*N)
  const int term = blockIdx.y;
  const int b = gid >> 13;
  const int n = gid & (NPTS - 1);
  const int base = b * NPTS;

  const float* PW = pw + (size_t)base * 3;
  const float* PP = pp + (size_t)base * 3;
  const float* TW = tw + (size_t)base * 3;
  const float* TP = tp + (size_t)base * 3;
  const int* I1P = idx_all + (0 * BATCH + b) * NPTS;  // NN pial for white (pred)
  const int* I2P = idx_all + (1 * BATCH + b) * NPTS;  // NN white for pial (pred)
  const int* I1T = idx_all + (2 * BATCH + b) * NPTS;  // NN pial for white (true)
  const int* I2T = idx_all + (3 * BATCH + b) * NPTS;  // NN white for pial (true)

  float sv;
  if (term == 0) {        // msn(yp_inner, yt_inner[i_pred_white])
    const int j = ipw[base + n];
    sv = diff_nrm2(ld3(PP, I1P[n]), ld3(PW, n), ld3(TP, I1T[j]), ld3(TW, j));
  } else if (term == 1) { // msn(yp_inner[i_true_white], yt_inner)
    const int k = itw[base + n];
    sv = diff_nrm2(ld3(PP, I1P[k]), ld3(PW, k), ld3(TP, I1T[n]), ld3(TW, n));
  } else if (term == 2) { // msn(yp_outer, yt_outer[i_pred_pial])
    const int j = ipp[base + n];
    sv = diff_nrm2(ld3(PP, n), ld3(PW, I2P[n]), ld3(TP, j), ld3(TW, I2T[j]));
  } else {                // msn(yp_outer[i_true_pial], yt_outer)
    const int k = itp[base + n];
    sv = diff_nrm2(ld3(PP, k), ld3(PW, I2P[k]), ld3(TP, n), ld3(TW, I2T[n]));
  }

  // Wave shuffle-reduce -> LDS -> single block sum.
  double ds = (double)sv;
  #pragma unroll
  for (int o = 32; o > 0; o >>= 1) ds += __shfl_down(ds, o, 64);
  if ((threadIdx.x & 63) == 0) sd[threadIdx.x >> 6] = ds;
  __syncthreads();

  if (threadIdx.x == 0) {
    const double bsum = sd[0] + sd[1] + sd[2] + sd[3];
    const double old = atomicAdd(acc, bsum);   // return forces completion
    // Data-dependency on 'old' orders the ticket bump after the acc add.
    const unsigned int inc = 1u + (unsigned int)(((unsigned long long)
                             __double_as_longlong(old)) & 0ull);
    const unsigned int total = gridDim.x * gridDim.y;   // 512
    const unsigned int t = atomicAdd(ticket, inc);
    if (t == total - 1u) {
      const double fin = atomicAdd(acc, 0.0);  // atomic read of the full sum
      out[0] = (float)(0.25 * fin / (double)BN);
    }
  }
}

// ---------------------------------------------------------------------------
extern "C" void kernel_launch(void* const* d_in, const int* in_sizes, int n_in,
                              void* d_out, int out_size, void* d_ws, size_t ws_size,
                              hipStream_t stream) {
  const float* pw = (const float*)d_in[0];
  const float* pp = (const float*)d_in[1];
  const float* tw = (const float*)d_in[2];
  const float* tp = (const float*)d_in[3];
  const int* ipw = (const int*)d_in[4];
  const int* itw = (const int*)d_in[5];
  const int* ipp = (const int*)d_in[6];
  const int* itp = (const int*)d_in[7];
  char* ws = (char*)d_ws;
  float* out = (float*)d_out;

  double* acc = (double*)ws;
  unsigned int* ticket = (unsigned int*)(ws + 8);
  int* idx_all = (int*)(ws + 64);
  unsigned long long* packed =
      (unsigned long long*)(ws + 64 + (size_t)NZB * NPTS * 4);

  init_kernel<<<(NZB * NPTS) / 256, 256, 0, stream>>>(packed, acc, ticket);

  dim3 grid_nn(NPTS / QBLK, SPL, NZB);
  nn_partial_kernel<<<grid_nn, 256, 0, stream>>>(pw, pp, tw, tp, packed);

  nn_rescan_kernel<<<(NZB * NPTS) / 32, 256, 0, stream>>>(
      pw, pp, tw, tp, packed, idx_all);

  dim3 grid_loss(BN / 256, 4);
  loss_final_kernel<<<grid_loss, 256, 0, stream>>>(
      pw, pp, tw, tp, ipw, itw, ipp, itp, idx_all, acc, ticket, out);
}